// Round 2
// baseline (599.856 us; speedup 1.0000x reference)
//
#include <hip/hip_runtime.h>
#include <math.h>

#define NTOT 8192
#define DDIM 64
#define DOUTD 32
#define NS_B 8          // K-splits for stage B (Y = x^T Q_S)
#define JS_D 8          // j-splits for stage D (out = Q_S P)
#define KDEG 16         // Chebyshev degree (terms 0..16), |r|<=0.5 -> trunc err ~5e-5

// ws layout (float offsets):
//  gF   @ 0        (64*64)
//  r    @ 4096     (8192)
//  s    @ 12288    (8192)
//  Yp   @ 20480    (NS_B * 64*8192)   partial Y slices
//  P    @ 4214784  (8192*32)
//  Dp   @ 4476928  (JS_D * 8192*32)   partial out slices
// total 6574080 floats = 26.3 MB
#define WS_GF 0
#define WS_R 4096
#define WS_S 12288
#define WS_YP 20480
#define YPSL (DDIM * NTOT)          // 524288 per slice
#define WS_P (WS_YP + NS_B * YPSL)  // 4214784
#define WS_DP (WS_P + NTOT * DOUTD) // 4476928
#define DPSL (NTOT * DOUTD)         // 262144 per slice

// ---------------- gF = F^T F / (||F^T F||_F + 1e-6) ----------------
__global__ __launch_bounds__(256) void k_prep_gF(const float* __restrict__ F,
                                                 float* __restrict__ gF) {
    __shared__ __align__(16) float Fl[64][68];
    __shared__ float red[256];
    int tid = threadIdx.x;
    for (int l = tid; l < 64 * 16; l += 256) {
        int d = l >> 4, c = (l & 15) << 2;
        *(float4*)&Fl[d][c] = *(const float4*)(F + d * 64 + c);
    }
    __syncthreads();
    int pa = tid >> 4, pb = tid & 15;
    int a0 = pa * 4, b0 = pb * 4;
    float acc[4][4] = {};
#pragma unroll 8
    for (int d = 0; d < 64; ++d) {
        float4 av = *(float4*)&Fl[d][a0];
        float4 bv = *(float4*)&Fl[d][b0];
        float aa[4] = {av.x, av.y, av.z, av.w};
        float bb[4] = {bv.x, bv.y, bv.z, bv.w};
#pragma unroll
        for (int i = 0; i < 4; ++i)
#pragma unroll
            for (int j = 0; j < 4; ++j) acc[i][j] += aa[i] * bb[j];
    }
    float ss = 0.f;
#pragma unroll
    for (int i = 0; i < 4; ++i)
#pragma unroll
        for (int j = 0; j < 4; ++j) ss += acc[i][j] * acc[i][j];
    red[tid] = ss;
    __syncthreads();
    for (int off = 128; off > 0; off >>= 1) {
        if (tid < off) red[tid] += red[tid + off];
        __syncthreads();
    }
    float scale = 1.f / (sqrtf(red[0]) + 1e-6f);
#pragma unroll
    for (int i = 0; i < 4; ++i)
#pragma unroll
        for (int j = 0; j < 4; ++j)
            gF[(a0 + i) * 64 + (b0 + j)] = acc[i][j] * scale;
}

// ---------------- per-column Chebyshev params ----------------
// a = gamma*LamS[j]; r = a/(1+sqrt(1-a^2)); s = 1/sqrt(1-a^2)
__global__ __launch_bounds__(256) void k_prep_cols(const float* __restrict__ Lam,
                                                   const float* __restrict__ gammap,
                                                   float* __restrict__ r_arr,
                                                   float* __restrict__ s_arr) {
    int j = blockIdx.x * 256 + threadIdx.x;
    if (j < NTOT) {
        float a = gammap[0] * Lam[j];
        float q = sqrtf(fmaxf(1.f - a * a, 1e-12f));
        r_arr[j] = a / (1.f + q);
        s_arr[j] = 1.f / q;
    }
}

// ---------------- stage B: Yp[ns] = partial of Y = x^T Q_S  [64 x 8192] ----------------
// grid (64 jblocks of 128 cols, NS_B n-splits), block 256 = 8 ti x 32 tj, thread tile 8x4
__global__ __launch_bounds__(256) void k_gemmB(const float* __restrict__ x,
                                               const float* __restrict__ Q,
                                               float* __restrict__ Yp) {
    __shared__ __align__(16) float xs[32][68];
    __shared__ __align__(16) float qs[32][132];
    int j0 = blockIdx.x * 128;
    int ns = blockIdx.y;
    int n0base = ns * (NTOT / NS_B);
    int tid = threadIdx.x;
    int ti = tid >> 5;  // i0 = 8*ti
    int tj = tid & 31;  // j = j0 + 4*tj + jj
    float acc[8][4] = {};
    for (int nc = 0; nc < (NTOT / NS_B) / 32; ++nc) {
        int n0 = n0base + nc * 32;
        for (int l = tid; l < 32 * 16; l += 256) {  // x chunk 32x64
            int nn = l >> 4, c = (l & 15) << 2;
            *(float4*)&xs[nn][c] = *(const float4*)(x + (size_t)(n0 + nn) * 64 + c);
        }
        for (int l = tid; l < 32 * 32; l += 256) {  // Q chunk 32x128
            int nn = l >> 5, c = (l & 31) << 2;
            *(float4*)&qs[nn][c] = *(const float4*)(Q + (size_t)(n0 + nn) * NTOT + j0 + c);
        }
        __syncthreads();
#pragma unroll 2
        for (int nn = 0; nn < 32; ++nn) {
            float4 xa = *(float4*)&xs[nn][ti * 8];
            float4 xb = *(float4*)&xs[nn][ti * 8 + 4];
            float4 qv = *(float4*)&qs[nn][tj * 4];
            float xv[8] = {xa.x, xa.y, xa.z, xa.w, xb.x, xb.y, xb.z, xb.w};
            float qq[4] = {qv.x, qv.y, qv.z, qv.w};
#pragma unroll
            for (int i = 0; i < 8; ++i)
#pragma unroll
                for (int j = 0; j < 4; ++j) acc[i][j] += xv[i] * qq[j];
        }
        __syncthreads();
    }
#pragma unroll
    for (int ii = 0; ii < 8; ++ii) {
        int i = ti * 8 + ii;
        float4 v = make_float4(acc[ii][0], acc[ii][1], acc[ii][2], acc[ii][3]);
        *(float4*)&Yp[(size_t)ns * YPSL + (size_t)i * NTOT + j0 + tj * 4] = v;
    }
}

// ---------------- stage C: fused Chebyshev resolvent + B_w projection ----------------
// u_j = sum_k c_k(a_j) T_k(gF) y_j ;  P[j][o] = sum_i B_w[o][i] u[i][j]
// grid 256 blocks x 32 cols, block 256 = 16 ti (4 rows) x 16 jt (2 cols)
__global__ __launch_bounds__(256) void k_cheb(const float* __restrict__ Yp,
                                              const float* __restrict__ gF,
                                              const float* __restrict__ r_arr,
                                              const float* __restrict__ s_arr,
                                              const float* __restrict__ Bw,
                                              float* __restrict__ P) {
    __shared__ __align__(16) float gfl[64][68];
    __shared__ __align__(16) float tb[2][64][34];
    __shared__ __align__(16) float bwl[32][68];
    int j0 = blockIdx.x * 32;
    int tid = threadIdx.x;
    for (int l = tid; l < 64 * 16; l += 256) {
        int k = l >> 4, c = (l & 15) << 2;
        *(float4*)&gfl[k][c] = *(const float4*)(gF + k * 64 + c);
    }
    for (int l = tid; l < 32 * 16; l += 256) {
        int o = l >> 4, c = (l & 15) << 2;
        *(float4*)&bwl[o][c] = *(const float4*)(Bw + o * 64 + c);
    }
    // T0 = Y slice (summing the NS_B partial slices here; no separate reduce kernel)
    for (int l = tid; l < 64 * 32; l += 256) {
        int k = l >> 5, c = l & 31;
        size_t base = (size_t)k * NTOT + j0 + c;
        float v = 0.f;
#pragma unroll
        for (int p = 0; p < NS_B; ++p) v += Yp[(size_t)p * YPSL + base];
        tb[0][k][c] = v;
    }
    __syncthreads();
    int ti = tid >> 4;  // i0 = 4*ti
    int jt = tid & 15;  // cols 2*jt, 2*jt+1
    int i0 = ti * 4;
    int jc0 = j0 + jt * 2;
    float r0 = r_arr[jc0], r1 = r_arr[jc0 + 1];
    float s0 = s_arr[jc0], s1 = s_arr[jc0 + 1];
    float rp0 = 1.f, rp1 = 1.f;
    float u[4][2];
#pragma unroll
    for (int ii = 0; ii < 4; ++ii) {
        u[ii][0] = s0 * tb[0][i0 + ii][jt * 2];
        u[ii][1] = s1 * tb[0][i0 + ii][jt * 2 + 1];
    }
    int cur = 0, prv = 1;
    for (int m = 1; m <= KDEG; ++m) {
        float mv[4][2] = {};
#pragma unroll 8
        for (int k = 0; k < 64; ++k) {
            float4 g = *(float4*)&gfl[k][i0];  // gF[k][i0..] == gF[i0..][k] (symmetric)
            float2 t = *(float2*)&tb[cur][k][jt * 2];
            mv[0][0] += g.x * t.x; mv[0][1] += g.x * t.y;
            mv[1][0] += g.y * t.x; mv[1][1] += g.y * t.y;
            mv[2][0] += g.z * t.x; mv[2][1] += g.z * t.y;
            mv[3][0] += g.w * t.x; mv[3][1] += g.w * t.y;
        }
        rp0 *= r0; rp1 *= r1;
        float c0 = 2.f * s0 * rp0, c1 = 2.f * s1 * rp1;
#pragma unroll
        for (int ii = 0; ii < 4; ++ii) {
            float t0, t1;
            if (m == 1) { t0 = mv[ii][0]; t1 = mv[ii][1]; }
            else {
                t0 = 2.f * mv[ii][0] - tb[prv][i0 + ii][jt * 2];
                t1 = 2.f * mv[ii][1] - tb[prv][i0 + ii][jt * 2 + 1];
            }
            tb[prv][i0 + ii][jt * 2] = t0;
            tb[prv][i0 + ii][jt * 2 + 1] = t1;
            u[ii][0] += c0 * t0;
            u[ii][1] += c1 * t1;
        }
        int tmp = cur; cur = prv; prv = tmp;
        __syncthreads();
    }
    // stash u in tb[0], then project with B_w
#pragma unroll
    for (int ii = 0; ii < 4; ++ii) {
        tb[0][i0 + ii][jt * 2] = u[ii][0];
        tb[0][i0 + ii][jt * 2 + 1] = u[ii][1];
    }
    __syncthreads();
    int jc = tid >> 3;          // 0..31 local col
    int o0 = (tid & 7) * 4;     // 4 outputs
    float pacc[4] = {0.f, 0.f, 0.f, 0.f};
#pragma unroll 8
    for (int i = 0; i < 64; ++i) {
        float uv = tb[0][i][jc];
#pragma unroll
        for (int o = 0; o < 4; ++o) pacc[o] += bwl[o0 + o][i] * uv;
    }
    *(float4*)&P[(size_t)(j0 + jc) * DOUTD + o0] =
        make_float4(pacc[0], pacc[1], pacc[2], pacc[3]);
}

// ---------------- stage D: Dp[js] = partial of out = Q_S @ P  [8192 x 32] ----------------
// grid (64 iblocks of 128 rows, JS_D j-splits), block 256 = 32 ti x 8 to, thread rows ti+32k
__global__ __launch_bounds__(256) void k_gemmD(const float* __restrict__ Q,
                                               const float* __restrict__ P,
                                               float* __restrict__ Dp) {
    __shared__ float qs[128 * 65];  // odd stride: bank = (row + j) % 32, conflict-free
    __shared__ __align__(16) float ps[64][36];
    int i0b = blockIdx.x * 128;
    int js = blockIdx.y;
    int j0s = js * (NTOT / JS_D);
    int tid = threadIdx.x;
    int ti = tid & 31;
    int to = tid >> 5;  // o0 = 4*to
    float acc[4][4] = {};
    for (int jt = 0; jt < (NTOT / JS_D) / 64; ++jt) {
        int j0 = j0s + jt * 64;
        for (int l = tid; l < 128 * 16; l += 256) {  // Q tile 128x64, scalar LDS writes (odd stride)
            int rr = l >> 4, c = (l & 15) << 2;
            float4 v = *(const float4*)(Q + (size_t)(i0b + rr) * NTOT + j0 + c);
            float* d = &qs[rr * 65 + c];
            d[0] = v.x; d[1] = v.y; d[2] = v.z; d[3] = v.w;
        }
        for (int l = tid; l < 64 * 8; l += 256) {  // P tile 64x32
            int rr = l >> 3, c = (l & 7) << 2;
            *(float4*)&ps[rr][c] = *(const float4*)(P + (size_t)(j0 + rr) * DOUTD + c);
        }
        __syncthreads();
#pragma unroll 4
        for (int j = 0; j < 64; ++j) {
            float4 pv = *(float4*)&ps[j][to * 4];
            float pp[4] = {pv.x, pv.y, pv.z, pv.w};
#pragma unroll
            for (int k = 0; k < 4; ++k) {
                float q = qs[(ti + 32 * k) * 65 + j];
#pragma unroll
                for (int o = 0; o < 4; ++o) acc[k][o] += q * pp[o];
            }
        }
        __syncthreads();
    }
#pragma unroll
    for (int k = 0; k < 4; ++k) {
        float4 v = make_float4(acc[k][0], acc[k][1], acc[k][2], acc[k][3]);
        *(float4*)&Dp[(size_t)js * DPSL + (size_t)(i0b + ti + 32 * k) * DOUTD + to * 4] = v;
    }
}

// ---------------- reduce JS_D partial outputs ----------------
__global__ __launch_bounds__(256) void k_reduce_out(const float* __restrict__ Dp,
                                                    float* __restrict__ out) {
    int idx = (blockIdx.x * 256 + threadIdx.x) * 4;
    float4 s = *(const float4*)(Dp + idx);
#pragma unroll
    for (int p = 1; p < JS_D; ++p) {
        float4 v = *(const float4*)(Dp + (size_t)p * DPSL + idx);
        s.x += v.x; s.y += v.y; s.z += v.z; s.w += v.w;
    }
    *(float4*)(out + idx) = s;
}

extern "C" void kernel_launch(void* const* d_in, const int* in_sizes, int n_in,
                              void* d_out, int out_size, void* d_ws, size_t ws_size,
                              hipStream_t stream) {
    const float* x = (const float*)d_in[0];
    const float* Q = (const float*)d_in[1];
    const float* Lam = (const float*)d_in[2];
    const float* F = (const float*)d_in[3];
    const float* Bw = (const float*)d_in[4];
    const float* gamma = (const float*)d_in[5];
    float* ws = (float*)d_ws;
    float* gF = ws + WS_GF;
    float* r_arr = ws + WS_R;
    float* s_arr = ws + WS_S;
    float* Yp = ws + WS_YP;
    float* P = ws + WS_P;
    float* Dp = ws + WS_DP;
    float* out = (float*)d_out;

    k_prep_gF<<<1, 256, 0, stream>>>(F, gF);
    k_prep_cols<<<32, 256, 0, stream>>>(Lam, gamma, r_arr, s_arr);
    k_gemmB<<<dim3(64, NS_B), 256, 0, stream>>>(x, Q, Yp);
    k_cheb<<<256, 256, 0, stream>>>(Yp, gF, r_arr, s_arr, Bw, P);
    k_gemmD<<<dim3(64, JS_D), 256, 0, stream>>>(Q, P, Dp);
    k_reduce_out<<<256, 256, 0, stream>>>(Dp, out);
}